// Round 1
// baseline (666.279 us; speedup 1.0000x reference)
//
#include <hip/hip_runtime.h>

#define WAVE 64
#define BLOCK 256
#define GRID 2048
#define EPSF 1e-8f

__global__ __launch_bounds__(BLOCK) void cosine_loss_kernel(
    const float* __restrict__ logits,
    const int* __restrict__ labels,
    float* __restrict__ out,
    int N, int C, float inv_n)
{
    const int lane    = threadIdx.x & (WAVE - 1);
    const int wave_id = (blockIdx.x * BLOCK + threadIdx.x) >> 6;
    const int n_waves = (gridDim.x * BLOCK) >> 6;

    const int nvec = C >> 2;          // number of full float4 chunks per row
    const int tail = nvec << 2;       // first scalar-tail column (== C when C%4==0)

    float local = 0.0f;               // lane-0 accumulates sum of (1-cos)/N

    for (int row = wave_id; row < N; row += n_waves) {
        const float* rowp = logits + (size_t)row * (size_t)C;

        // lane 0 grabs the label element (L1/L2 hit: wave streams this row anyway)
        float dot = 0.0f;
        if (lane == 0) {
            int lbl = labels[row];
            dot = rowp[lbl];
        }

        // coalesced float4 sum of squares
        const float4* rowp4 = (const float4*)rowp;
        float ss = 0.0f;
        for (int c = lane; c < nvec; c += WAVE) {
            float4 v = rowp4[c];
            ss = fmaf(v.x, v.x, ss);
            ss = fmaf(v.y, v.y, ss);
            ss = fmaf(v.z, v.z, ss);
            ss = fmaf(v.w, v.w, ss);
        }
        // scalar tail (no-op for C % 4 == 0)
        for (int c = tail + lane; c < C; c += WAVE) {
            float v = rowp[c];
            ss = fmaf(v, v, ss);
        }

        // wave reduction (64 lanes)
        #pragma unroll
        for (int off = 32; off > 0; off >>= 1)
            ss += __shfl_down(ss, off, WAVE);

        if (lane == 0) {
            float norm = sqrtf(ss);
            float cosv = dot / fmaxf(norm, EPSF);
            local += (1.0f - cosv) * inv_n;
        }
    }

    // block reduction: one partial per wave, then one atomic per block
    __shared__ float sdata[BLOCK / WAVE];
    const int w = threadIdx.x >> 6;
    if (lane == 0) sdata[w] = local;
    __syncthreads();
    if (threadIdx.x == 0) {
        float s = 0.0f;
        #pragma unroll
        for (int i = 0; i < BLOCK / WAVE; ++i) s += sdata[i];
        atomicAdd(out, s);
    }
}

extern "C" void kernel_launch(void* const* d_in, const int* in_sizes, int n_in,
                              void* d_out, int out_size, void* d_ws, size_t ws_size,
                              hipStream_t stream) {
    const float* logits = (const float*)d_in[0];
    const int*   labels = (const int*)d_in[1];
    float*       out    = (float*)d_out;

    const int N = in_sizes[1];
    const int C = in_sizes[0] / N;
    const float inv_n = 1.0f / (float)N;

    // d_out is poisoned to 0xAA before every timed launch — zero it (capturable)
    hipMemsetAsync(d_out, 0, sizeof(float), stream);

    cosine_loss_kernel<<<GRID, BLOCK, 0, stream>>>(logits, labels, out, N, C, inv_n);
}

// Round 2
// 654.880 us; speedup vs baseline: 1.0174x; 1.0174x over previous
//
#include <hip/hip_runtime.h>

#define WAVE 64
#define BLOCK 256
#define GRID 2048
#define EPSF 1e-8f

typedef float f4 __attribute__((ext_vector_type(4)));

__global__ __launch_bounds__(BLOCK) void cosine_loss_kernel(
    const float* __restrict__ logits,
    const int* __restrict__ labels,
    float* __restrict__ out,
    int N, int C, float inv_n)
{
    const int lane    = threadIdx.x & (WAVE - 1);
    const int wave_id = (blockIdx.x * BLOCK + threadIdx.x) >> 6;
    const int n_waves = (gridDim.x * BLOCK) >> 6;

    const int nvec = C >> 2;          // full float4 chunks per row
    const int tail = nvec << 2;       // first scalar-tail column

    float local = 0.0f;               // per-lane partial of mean(1-cos)

    int base = wave_id;

    // ---- main path: 4 rows in flight per wave (4x memory-level parallelism)
    for (; base + 3 * n_waves < N; base += 4 * n_waves) {
        const int r0 = base;
        const int r1 = base + n_waves;
        const int r2 = base + 2 * n_waves;
        const int r3 = base + 3 * n_waves;

        const f4* p0 = (const f4*)(logits + (size_t)r0 * (size_t)C);
        const f4* p1 = (const f4*)(logits + (size_t)r1 * (size_t)C);
        const f4* p2 = (const f4*)(logits + (size_t)r2 * (size_t)C);
        const f4* p3 = (const f4*)(logits + (size_t)r3 * (size_t)C);

        // lanes 0..3 fetch label + dot for their row, hoisted above the stream
        float dotk = 0.0f;
        if (lane < 4) {
            const int rk = base + lane * n_waves;
            const int lbl = labels[rk];
            dotk = logits[(size_t)rk * (size_t)C + (size_t)lbl];
        }

        float s0 = 0.0f, s1 = 0.0f, s2 = 0.0f, s3 = 0.0f;
        for (int c = lane; c < nvec; c += WAVE) {
            f4 a = __builtin_nontemporal_load(&p0[c]);
            f4 b = __builtin_nontemporal_load(&p1[c]);
            f4 d = __builtin_nontemporal_load(&p2[c]);
            f4 e = __builtin_nontemporal_load(&p3[c]);
            s0 = fmaf(a.x, a.x, fmaf(a.y, a.y, fmaf(a.z, a.z, fmaf(a.w, a.w, s0))));
            s1 = fmaf(b.x, b.x, fmaf(b.y, b.y, fmaf(b.z, b.z, fmaf(b.w, b.w, s1))));
            s2 = fmaf(d.x, d.x, fmaf(d.y, d.y, fmaf(d.z, d.z, fmaf(d.w, d.w, s2))));
            s3 = fmaf(e.x, e.x, fmaf(e.y, e.y, fmaf(e.z, e.z, fmaf(e.w, e.w, s3))));
        }
        // scalar tail (no-op for C % 4 == 0)
        for (int c = tail + lane; c < C; c += WAVE) {
            float v0 = logits[(size_t)r0 * C + c];
            float v1 = logits[(size_t)r1 * C + c];
            float v2 = logits[(size_t)r2 * C + c];
            float v3 = logits[(size_t)r3 * C + c];
            s0 = fmaf(v0, v0, s0);
            s1 = fmaf(v1, v1, s1);
            s2 = fmaf(v2, v2, s2);
            s3 = fmaf(v3, v3, s3);
        }

        // butterfly: every lane ends with all four row-sums
        #pragma unroll
        for (int off = 1; off < WAVE; off <<= 1) {
            s0 += __shfl_xor(s0, off, WAVE);
            s1 += __shfl_xor(s1, off, WAVE);
            s2 += __shfl_xor(s2, off, WAVE);
            s3 += __shfl_xor(s3, off, WAVE);
        }

        if (lane < 4) {
            const float ss = (lane == 0) ? s0 : (lane == 1) ? s1 : (lane == 2) ? s2 : s3;
            const float norm = sqrtf(ss);
            local += (1.0f - dotk / fmaxf(norm, EPSF)) * inv_n;
        }
    }

    // ---- remainder rows (single-row path)
    for (; base < N; base += n_waves) {
        const f4* p = (const f4*)(logits + (size_t)base * (size_t)C);
        float dot = 0.0f;
        if (lane == 0) {
            const int lbl = labels[base];
            dot = logits[(size_t)base * (size_t)C + (size_t)lbl];
        }
        float ss = 0.0f;
        for (int c = lane; c < nvec; c += WAVE) {
            f4 v = __builtin_nontemporal_load(&p[c]);
            ss = fmaf(v.x, v.x, fmaf(v.y, v.y, fmaf(v.z, v.z, fmaf(v.w, v.w, ss))));
        }
        for (int c = tail + lane; c < C; c += WAVE) {
            float v = logits[(size_t)base * C + c];
            ss = fmaf(v, v, ss);
        }
        #pragma unroll
        for (int off = 32; off > 0; off >>= 1)
            ss += __shfl_down(ss, off, WAVE);
        if (lane == 0) {
            const float norm = sqrtf(ss);
            local += (1.0f - dot / fmaxf(norm, EPSF)) * inv_n;
        }
    }

    // ---- block reduction: wave butterfly-down, one LDS slot per wave, one atomic per block
    #pragma unroll
    for (int off = 32; off > 0; off >>= 1)
        local += __shfl_down(local, off, WAVE);

    __shared__ float sdata[BLOCK / WAVE];
    const int w = threadIdx.x >> 6;
    if (lane == 0) sdata[w] = local;
    __syncthreads();
    if (threadIdx.x == 0) {
        float s = 0.0f;
        #pragma unroll
        for (int i = 0; i < BLOCK / WAVE; ++i) s += sdata[i];
        atomicAdd(out, s);
    }
}

extern "C" void kernel_launch(void* const* d_in, const int* in_sizes, int n_in,
                              void* d_out, int out_size, void* d_ws, size_t ws_size,
                              hipStream_t stream) {
    const float* logits = (const float*)d_in[0];
    const int*   labels = (const int*)d_in[1];
    float*       out    = (float*)d_out;

    const int N = in_sizes[1];
    const int C = in_sizes[0] / N;
    const float inv_n = 1.0f / (float)N;

    // d_out is poisoned to 0xAA before every timed launch — zero it (capturable)
    hipMemsetAsync(d_out, 0, sizeof(float), stream);

    cosine_loss_kernel<<<GRID, BLOCK, 0, stream>>>(logits, labels, out, N, C, inv_n);
}